// Round 15
// baseline (1233.808 us; speedup 1.0000x reference)
//
#include <hip/hip_runtime.h>
#include <math.h>

#define DEV __device__ __forceinline__

#define LOG2E 1.4426950408889634f

typedef _Float16 h2v __attribute__((ext_vector_type(2)));

DEV float fexp(float x)  { return __builtin_amdgcn_exp2f(LOG2E * x); }
DEV float fsigm(float x) { return __builtin_amdgcn_rcpf(1.0f + __builtin_amdgcn_exp2f(-LOG2E * x)); }
DEV float ftanh(float x) { return 1.0f - 2.0f * __builtin_amdgcn_rcpf(__builtin_amdgcn_exp2f(2.0f * LOG2E * x) + 1.0f); }
DEV float lrelu02(float x) { return x > 0.0f ? x : 0.2f * x; }
DEV float fdot2(h2v a, h2v b, float c) { return __builtin_amdgcn_fdot2(a, b, c, false); }
DEV int aload(const int* p) {
    return __hip_atomic_load(p, __ATOMIC_RELAXED, __HIP_MEMORY_SCOPE_AGENT);
}
DEV void astore(int* p, int v) {
    __hip_atomic_store(p, v, __ATOMIC_RELAXED, __HIP_MEMORY_SCOPE_AGENT);
}
DEV unsigned short f2bf(float f) {
    unsigned u = __float_as_uint(f);
    return (unsigned short)((u + 0x7FFFu + ((u >> 16) & 1u)) >> 16);
}
DEV void unpack8(uint4 w, float4& lo, float4& hi) {
    lo.x = __uint_as_float(w.x << 16); lo.y = __uint_as_float(w.x & 0xFFFF0000u);
    lo.z = __uint_as_float(w.y << 16); lo.w = __uint_as_float(w.y & 0xFFFF0000u);
    hi.x = __uint_as_float(w.z << 16); hi.y = __uint_as_float(w.z & 0xFFFF0000u);
    hi.z = __uint_as_float(w.w << 16); hi.w = __uint_as_float(w.w & 0xFFFF0000u);
}
DEV float readl(float v, int l) {
    return __int_as_float(__builtin_amdgcn_readlane(__float_as_int(v), l));
}
#define QB(v, ctrl) __int_as_float(__builtin_amdgcn_mov_dpp(__float_as_int(v), ctrl, 0xF, 0xF, true))

// ---------------------------------------------------------------------------
// Mega-front (unchanged from r13/r14): LSTM f16-dot2 || hist->scan->scatter ||
// att1P || Wxp(bf16) || M2.
// ---------------------------------------------------------------------------
__global__ __launch_bounds__(512, 2) void k_front(
    const float* __restrict__ ts,
    const float* __restrict__ Wih0, const float* __restrict__ Whh0, const float* __restrict__ b0,
    const float* __restrict__ Wih1, const float* __restrict__ Whh1, const float* __restrict__ b1,
    const float* __restrict__ W1, const float* __restrict__ A1,
    const float* __restrict__ W2, const float* __restrict__ A2,
    float* __restrict__ tsb, float* __restrict__ attfix, float* __restrict__ m2g,
    const int* __restrict__ ei, int* __restrict__ deg, int* __restrict__ epos,
    const float* __restrict__ nf, unsigned short* __restrict__ Wxp,
    float* __restrict__ asrcP, float* __restrict__ adstP,
    int* __restrict__ rowptr, int* __restrict__ bsum,
    int* __restrict__ esrc, int* __restrict__ flags,
    int N, int E, int T, int NCH)
{
    __shared__ __align__(16) _Float16 h0h[2][64], h1h[2][64];
    __shared__ __align__(16) float tsbig[21504];   // 84KB pad -> 1 block/CU
    __shared__ float m1s[128];
    __shared__ int iwsum[8];
    __shared__ int stmp[512];
    const int tid = threadIdx.x;
    const int bid = blockIdx.x;

    auto signalflag = [&](int* f) {
        __syncthreads();
        if (tid == 0) {
            __threadfence();
            __hip_atomic_fetch_add(f, 1, __ATOMIC_RELEASE, __HIP_MEMORY_SCOPE_AGENT);
        }
    };
    auto waitflag = [&](int* f, int tgt) {
        if (tid == 0) {
            while (__hip_atomic_load(f, __ATOMIC_ACQUIRE, __HIP_MEMORY_SCOPE_AGENT) < tgt)
                __builtin_amdgcn_s_sleep(8);
        }
        __syncthreads();
    };

    if (bid == 0) {
        // ================= LSTM =================
        const int seg = tid >> 8;
        const int idx = tid & 255;
        const int u = idx >> 2;
        const int q = idx & 3;
        const int row = q * 64 + u;
        float* tss = tsbig;

        for (int i = tid; i < 3 * T && i < 512; i += 512) tss[i] = ts[i];
        if (tid < 64) {
            h0h[0][tid] = (_Float16)0.f; h0h[1][tid] = (_Float16)0.f;
            h1h[0][tid] = (_Float16)0.f; h1h[1][tid] = (_Float16)0.f;
        }
        __syncthreads();

        if (seg == 0) {
            h2v wa[32];
            float wih[3];
            float bias = b0[row];
            wih[0] = Wih0[row*3+0]; wih[1] = Wih0[row*3+1]; wih[2] = Wih0[row*3+2];
#pragma unroll
            for (int k = 0; k < 32; k++) {
                h2v w; w.x = (_Float16)Whh0[row*64 + 2*k]; w.y = (_Float16)Whh0[row*64 + 2*k + 1];
                wa[k] = w;
            }
            float creg = 0.0f;
            for (int k = 0; k <= T; ++k) {
                if (k < T) {
                    const h2v* hp = (const h2v*)h0h[(k + 1) & 1];
                    float a0 = bias, a1 = 0.f, a2 = 0.f, a3 = 0.f;
                    a0 = fmaf(tss[3*k+0], wih[0], a0);
                    a1 = fmaf(tss[3*k+1], wih[1], a1);
                    a2 = fmaf(tss[3*k+2], wih[2], a2);
#pragma unroll
                    for (int p = 0; p < 32; p += 4) {
                        a0 = fdot2(wa[p+0], hp[p+0], a0);
                        a1 = fdot2(wa[p+1], hp[p+1], a1);
                        a2 = fdot2(wa[p+2], hp[p+2], a2);
                        a3 = fdot2(wa[p+3], hp[p+3], a3);
                    }
                    float mine = (a0 + a1) + (a2 + a3);
                    float gi = QB(mine, 0x00);
                    float gf = QB(mine, 0x55);
                    float gg = QB(mine, 0xAA);
                    float go = QB(mine, 0xFF);
                    creg = fsigm(gf) * creg + fsigm(gi) * ftanh(gg);
                    float h = fsigm(go) * ftanh(creg);
                    if (q == 0) h0h[k & 1][u] = (_Float16)h;
                }
                __syncthreads();
            }
            if (tid < 128) {
                const _Float16* hf = h1h[(T - 1) & 1];
                float acc = 0.f;
#pragma unroll
                for (int kk = 0; kk < 64; kk++)
                    acc = fmaf((float)hf[kk], W1[(16 + kk) * 128 + tid], acc);
                tsb[tid] = acc;
                m1s[tid] = acc;
            }
            __syncthreads();
            if (tid < 8) {
                int half = tid >> 2, h = tid & 3;
                const float* a1p = A1 + (size_t)half * 512 + h;
                float acc = 0.f;
                for (int c = 0; c < 128; c++) acc = fmaf(m1s[c], a1p[c * 4], acc);
                attfix[tid] = acc;
            }
        } else {
            h2v wa[32], wb[32];
            float bias = b1[row];
#pragma unroll
            for (int k = 0; k < 32; k++) {
                h2v w; w.x = (_Float16)Whh1[row*64 + 2*k]; w.y = (_Float16)Whh1[row*64 + 2*k + 1];
                wa[k] = w;
            }
#pragma unroll
            for (int k = 0; k < 32; k++) {
                h2v w; w.x = (_Float16)Wih1[row*64 + 2*k]; w.y = (_Float16)Wih1[row*64 + 2*k + 1];
                wb[k] = w;
            }
            float creg = 0.0f;
            for (int k = 0; k <= T; ++k) {
                if (k >= 1) {
                    const h2v* h1p = (const h2v*)h1h[k & 1];
                    const h2v* h0p = (const h2v*)h0h[(k + 1) & 1];
                    float a0 = bias, a1 = 0.f, a2 = 0.f, a3 = 0.f;
#pragma unroll
                    for (int p = 0; p < 32; p += 4) {
                        a0 = fdot2(wa[p+0], h1p[p+0], a0);
                        a1 = fdot2(wa[p+1], h1p[p+1], a1);
                        a2 = fdot2(wa[p+2], h1p[p+2], a2);
                        a3 = fdot2(wa[p+3], h1p[p+3], a3);
                    }
#pragma unroll
                    for (int p = 0; p < 32; p += 4) {
                        a0 = fdot2(wb[p+0], h0p[p+0], a0);
                        a1 = fdot2(wb[p+1], h0p[p+1], a1);
                        a2 = fdot2(wb[p+2], h0p[p+2], a2);
                        a3 = fdot2(wb[p+3], h0p[p+3], a3);
                    }
                    float mine = (a0 + a1) + (a2 + a3);
                    float gi = QB(mine, 0x00);
                    float gf = QB(mine, 0x55);
                    float gg = QB(mine, 0xAA);
                    float go = QB(mine, 0xFF);
                    creg = fsigm(gf) * creg + fsigm(gi) * ftanh(gg);
                    float h = fsigm(go) * ftanh(creg);
                    if (q == 0) h1h[(k + 1) & 1][u] = (_Float16)h;
                }
                __syncthreads();
            }
            __syncthreads();
        }
        return;
    }

    // ================= workers =================
    const int W = gridDim.x - 1;
    const int wid = bid - 1;

    {
        int g = wid * 512 + tid, stride = W * 512;
        for (int e = g; e < E; e += stride)
            epos[e] = atomicAdd(&deg[ei[E + e]], 1);
    }
    signalflag(&flags[0]);

    if (wid < NCH) {
        waitflag(&flags[0], W);
        int base = wid * 2048 + tid * 4;
        int d0 = base + 0 < N ? aload(&deg[base + 0]) : 0;
        int d1 = base + 1 < N ? aload(&deg[base + 1]) : 0;
        int d2 = base + 2 < N ? aload(&deg[base + 2]) : 0;
        int d3 = base + 3 < N ? aload(&deg[base + 3]) : 0;
        int tsum = d0 + d1 + d2 + d3;
        int lane = tid & 63, wv = tid >> 6;
        int incl = tsum;
#pragma unroll
        for (int off = 1; off < 64; off <<= 1) {
            int t = __shfl_up(incl, off, 64);
            if (lane >= off) incl += t;
        }
        if (lane == 63) iwsum[wv] = incl;
        __syncthreads();
        int woff = 0;
#pragma unroll
        for (int w = 0; w < 8; w++) if (w < wv) woff += iwsum[w];
        int tex = woff + incl - tsum;
        if (base + 0 < N) rowptr[base + 0] = tex;
        if (base + 1 < N) rowptr[base + 1] = tex + d0;
        if (base + 2 < N) rowptr[base + 2] = tex + d0 + d1;
        if (base + 3 < N) rowptr[base + 3] = tex + d0 + d1 + d2;
        if (tid == 511) astore(&bsum[wid], woff + incl);
        signalflag(&flags[1]);
        waitflag(&flags[2], 1);
        int off2 = aload(&bsum[wid]);
#pragma unroll
        for (int i = 0; i < 4; i++) {
            int idx = base + i;
            if (idx < N) {
                int v = rowptr[idx] + off2;
                astore(&rowptr[idx], v);
            }
        }
        if (wid == 0 && tid == 0) astore(&rowptr[N], E);
        signalflag(&flags[3]);
    } else if (wid == NCH) {
        waitflag(&flags[1], NCH);
        int v = tid < NCH ? aload(&bsum[tid]) : 0;
        stmp[tid] = v;
        __syncthreads();
        for (int off = 1; off < 512; off <<= 1) {
            int t = (tid >= off) ? stmp[tid - off] : 0;
            __syncthreads();
            stmp[tid] += t;
            __syncthreads();
        }
        if (tid < NCH) astore(&bsum[tid], stmp[tid] - v);
        signalflag(&flags[2]);
#pragma unroll
        for (int e = tid; e < 1024; e += 512) {
            int k = e >> 3, h8 = e & 7, half = h8 >> 2, h = h8 & 3;
            const float* w2p = W2 + (size_t)k * 128;
            const float* a2p = A2 + (size_t)half * 512 + h;
            float acc = 0.f;
            for (int c = 0; c < 128; c++) acc = fmaf(w2p[c], a2p[c * 4], acc);
            m2g[e] = acc;
        }
    } else {
        const int AW = W - NCH - 1;
        const int aw = wid - NCH - 1;
        if (tid < 128) {
            int k = tid >> 3, h8 = tid & 7, half = h8 >> 2, h = h8 & 3;
            const float* a1p = A1 + (size_t)half * 512 + h;
            const float* w1p = W1 + (size_t)k * 128;
            float acc = 0.f;
            for (int c = 0; c < 128; c++) acc = fmaf(w1p[c], a1p[c * 4], acc);
            m1s[tid] = acc;
        }
        __syncthreads();
        float m1r[128];
#pragma unroll
        for (int i = 0; i < 128; i++) m1r[i] = m1s[i];
        {
            int gt = aw * 512 + tid;
            int tstride = AW * 512;
            for (int n = gt; n < N; n += tstride) {
                const float4* nfr = (const float4*)(nf + (size_t)n * 16);
                float4 f0 = nfr[0], f1 = nfr[1], f2 = nfr[2], f3 = nfr[3];
                float xk[16] = {f0.x,f0.y,f0.z,f0.w, f1.x,f1.y,f1.z,f1.w,
                                f2.x,f2.y,f2.z,f2.w, f3.x,f3.y,f3.z,f3.w};
                float as0=0,as1=0,as2=0,as3=0, ad0=0,ad1=0,ad2=0,ad3=0;
#pragma unroll
                for (int k = 0; k < 16; k++) {
                    float xv = xk[k];
                    as0 = fmaf(xv, m1r[k*8+0], as0); as1 = fmaf(xv, m1r[k*8+1], as1);
                    as2 = fmaf(xv, m1r[k*8+2], as2); as3 = fmaf(xv, m1r[k*8+3], as3);
                    ad0 = fmaf(xv, m1r[k*8+4], ad0); ad1 = fmaf(xv, m1r[k*8+5], ad1);
                    ad2 = fmaf(xv, m1r[k*8+6], ad2); ad3 = fmaf(xv, m1r[k*8+7], ad3);
                }
                float4 o1; o1.x=as0; o1.y=as1; o1.z=as2; o1.w=as3;
                float4 o2; o2.x=ad0; o2.y=ad1; o2.z=ad2; o2.w=ad3;
                ((float4*)asrcP)[n] = o1;
                ((float4*)adstP)[n] = o2;
            }
        }
        {
            int lane = tid & 63;
            int bw = aw * 8 + (tid >> 6);
            int half = bw & 1;
            int col = lane + 64 * half;
            float wreg[16];
#pragma unroll
            for (int k = 0; k < 16; k++) wreg[k] = W1[k * 128 + col];
            int nstride = AW * 4;
            for (int n = (bw >> 1); n < N; n += nstride) {
                int nu = __builtin_amdgcn_readfirstlane(n);
                const float4* xr = (const float4*)(nf + (size_t)nu * 16);
                float4 x0 = xr[0], x1 = xr[1], x2 = xr[2], x3 = xr[3];
                float acc = 0.f;
                acc = fmaf(x0.x, wreg[0],  acc); acc = fmaf(x0.y, wreg[1],  acc);
                acc = fmaf(x0.z, wreg[2],  acc); acc = fmaf(x0.w, wreg[3],  acc);
                acc = fmaf(x1.x, wreg[4],  acc); acc = fmaf(x1.y, wreg[5],  acc);
                acc = fmaf(x1.z, wreg[6],  acc); acc = fmaf(x1.w, wreg[7],  acc);
                acc = fmaf(x2.x, wreg[8],  acc); acc = fmaf(x2.y, wreg[9],  acc);
                acc = fmaf(x2.z, wreg[10], acc); acc = fmaf(x2.w, wreg[11], acc);
                acc = fmaf(x3.x, wreg[12], acc); acc = fmaf(x3.y, wreg[13], acc);
                acc = fmaf(x3.z, wreg[14], acc); acc = fmaf(x3.w, wreg[15], acc);
                Wxp[(size_t)nu * 128 + col] = f2bf(acc);
            }
        }
    }

    waitflag(&flags[3], NCH);
    {
        int g = wid * 512 + tid, stride = W * 512;
        for (int e = g; e < E; e += stride) {
            int s = ei[e], d = ei[E + e];
            esrc[aload(&rowptr[d]) + epos[e]] = s;
        }
    }
}

// ---------------------------------------------------------------------------
// Fused GAT layer-1 aggregate + layer-2 projections, register-slimmed:
//  - no chunk-0 exp cache (pass B recomputes; asrc is L2-resident)
//  - tsb load + csum*tsb deferred to the epilogue
//  - shfl broadcasts consumed immediately (no xks staging)
// __launch_bounds__(512,8): natural VGPR should now fit the <=64 bin
// without (significant) spill -> 8 waves/SIMD, 4 blocks/CU at 37KB LDS.
// ---------------------------------------------------------------------------
__global__ __launch_bounds__(512, 8) void k_msg1(
    const int* __restrict__ rowptr, const int* __restrict__ esrc,
    const float* __restrict__ asrc, const float* __restrict__ adst,
    const unsigned short* __restrict__ Wx, const float* __restrict__ tsb,
    const float* __restrict__ attfix,
    const float* __restrict__ W2, const float* __restrict__ m2g,
    unsigned short* __restrict__ Wx2, float* __restrict__ asrc2,
    float* __restrict__ adst2, int N)
{
    __shared__ unsigned short w2s[16384];   // 32KB: W2 bf16 [k][c]
    __shared__ float m2p[128 * 9];          // padded M2
    int tid = threadIdx.x;
    for (int i = tid; i < 16384; i += 512) w2s[i] = f2bf(W2[i]);
    for (int i = tid; i < 1024; i += 512) m2p[(i >> 3) * 9 + (i & 7)] = m2g[i];
    __syncthreads();

    int lane = tid & 63;
    int grp = lane >> 4;
    int gl = lane & 15;
    int wbase = lane & 48;
    int gw = (blockIdx.x * blockDim.x + tid) >> 6;
    int waves = (gridDim.x * blockDim.x) >> 6;

    float cc0 = attfix[0] + attfix[4];
    float cc1 = attfix[1] + attfix[5];
    float cc2 = attfix[2] + attfix[6];
    float cc3 = attfix[3] + attfix[7];

    for (int m = gw; m * 4 < N; m += waves) {
        int n = m * 4 + grp;
        bool nv = n < N;
        int beg = nv ? rowptr[n] : 0;
        int end = nv ? rowptr[n + 1] : 0;
        float4 ad = {0,0,0,0};
        if (nv) ad = ((const float4*)adst)[n];
        ad.x += cc0; ad.y += cc1; ad.z += cc2; ad.w += cc3;

        // pass A: denominators (no exp caching)
        float d0 = 0.f, d1 = 0.f, d2 = 0.f, d3 = 0.f;
        for (int c = beg; c < end; c += 16) {
            int e = c + gl;
            bool v = e < end;
            int s = v ? esrc[e] : 0;
            float4 a = ((const float4*)asrc)[s];
            if (v) {
                d0 += fexp(lrelu02(a.x + ad.x));
                d1 += fexp(lrelu02(a.y + ad.y));
                d2 += fexp(lrelu02(a.z + ad.z));
                d3 += fexp(lrelu02(a.w + ad.w));
            }
        }
#pragma unroll
        for (int off = 8; off; off >>= 1) {
            d0 += __shfl_xor(d0, off, 64);
            d1 += __shfl_xor(d1, off, 64);
            d2 += __shfl_xor(d2, off, 64);
            d3 += __shfl_xor(d3, off, 64);
        }
        float r0 = __builtin_amdgcn_rcpf(d0 + 2e-9f);
        float r1 = __builtin_amdgcn_rcpf(d1 + 2e-9f);
        float r2 = __builtin_amdgcn_rcpf(d2 + 2e-9f);
        float r3 = __builtin_amdgcn_rcpf(d3 + 2e-9f);

        // pass B: gather-accumulate (exps recomputed)
        float4 acc0 = {0,0,0,0}, acc1 = {0,0,0,0};
        for (int c = beg; c < end; c += 16) {
            int e = c + gl;
            bool v = e < end;
            int s = v ? esrc[e] : 0;
            float4 a = ((const float4*)asrc)[s];
            float cf = 0.f;
            if (v) {
                cf = fexp(lrelu02(a.x + ad.x)) * r0
                   + fexp(lrelu02(a.y + ad.y)) * r1
                   + fexp(lrelu02(a.z + ad.z)) * r2
                   + fexp(lrelu02(a.w + ad.w)) * r3;
            }
#pragma unroll 4
            for (int jj = 0; jj < 16; ++jj) {
                float cj = __shfl(cf, wbase + jj, 64);
                if (cj > 0.f) {
                    int sj = __shfl(s, wbase + jj, 64);
                    uint4 w = ((const uint4*)(Wx + (size_t)sj * 128))[gl];
                    float4 lo, hi; unpack8(w, lo, hi);
                    acc0.x = fmaf(cj, lo.x, acc0.x); acc0.y = fmaf(cj, lo.y, acc0.y);
                    acc0.z = fmaf(cj, lo.z, acc0.z); acc0.w = fmaf(cj, lo.w, acc0.w);
                    acc1.x = fmaf(cj, hi.x, acc1.x); acc1.y = fmaf(cj, hi.y, acc1.y);
                    acc1.z = fmaf(cj, hi.z, acc1.z); acc1.w = fmaf(cj, hi.w, acc1.w);
                }
            }
        }
        // epilogue: + csum*tsb, /4, ELU
        {
            float csum = d0*r0 + d1*r1 + d2*r2 + d3*r3;
            float4 tb0 = ((const float4*)tsb)[gl*2];
            float4 tb1 = ((const float4*)tsb)[gl*2+1];
            acc0.x = fmaf(csum, tb0.x, acc0.x); acc0.y = fmaf(csum, tb0.y, acc0.y);
            acc0.z = fmaf(csum, tb0.z, acc0.z); acc0.w = fmaf(csum, tb0.w, acc0.w);
            acc1.x = fmaf(csum, tb1.x, acc1.x); acc1.y = fmaf(csum, tb1.y, acc1.y);
            acc1.z = fmaf(csum, tb1.z, acc1.z); acc1.w = fmaf(csum, tb1.w, acc1.w);
        }
        acc0.x *= 0.25f; acc0.y *= 0.25f; acc0.z *= 0.25f; acc0.w *= 0.25f;
        acc1.x *= 0.25f; acc1.y *= 0.25f; acc1.z *= 0.25f; acc1.w *= 0.25f;
        acc0.x = acc0.x > 0.f ? acc0.x : expm1f(acc0.x);
        acc0.y = acc0.y > 0.f ? acc0.y : expm1f(acc0.y);
        acc0.z = acc0.z > 0.f ? acc0.z : expm1f(acc0.z);
        acc0.w = acc0.w > 0.f ? acc0.w : expm1f(acc0.w);
        acc1.x = acc1.x > 0.f ? acc1.x : expm1f(acc1.x);
        acc1.y = acc1.y > 0.f ? acc1.y : expm1f(acc1.y);
        acc1.z = acc1.z > 0.f ? acc1.z : expm1f(acc1.z);
        acc1.w = acc1.w > 0.f ? acc1.w : expm1f(acc1.w);

        float xo[8] = {acc0.x,acc0.y,acc0.z,acc0.w, acc1.x,acc1.y,acc1.z,acc1.w};

        // Wx2: x1 broadcast via shfl, consumed immediately
        float4 wa0 = {0,0,0,0}, wa1 = {0,0,0,0};
        const uint4* w2v4 = (const uint4*)w2s;
        for (int j = 0; j < 16; ++j) {
            int src = wbase + j;
#pragma unroll
            for (int e = 0; e < 8; ++e) {
                float xv = __shfl(xo[e], src, 64);
                uint4 w = w2v4[(8*j + e) * 16 + gl];
                float4 lo, hi; unpack8(w, lo, hi);
                wa0.x = fmaf(xv, lo.x, wa0.x); wa0.y = fmaf(xv, lo.y, wa0.y);
                wa0.z = fmaf(xv, lo.z, wa0.z); wa0.w = fmaf(xv, lo.w, wa0.w);
                wa1.x = fmaf(xv, hi.x, wa1.x); wa1.y = fmaf(xv, hi.y, wa1.y);
                wa1.z = fmaf(xv, hi.z, wa1.z); wa1.w = fmaf(xv, hi.w, wa1.w);
            }
        }
        // att2 partials over own k-range
        float aacc[8] = {0,0,0,0,0,0,0,0};
#pragma unroll
        for (int kk = 0; kk < 8; ++kk) {
            const float* mrow = &m2p[(8 * gl + kk) * 9];
            float xv = xo[kk];
#pragma unroll
            for (int h = 0; h < 8; ++h) aacc[h] = fmaf(xv, mrow[h], aacc[h]);
        }
#pragma unroll
        for (int off = 8; off; off >>= 1) {
#pragma unroll
            for (int h = 0; h < 8; ++h) aacc[h] += __shfl_xor(aacc[h], off, 64);
        }
        if (nv) {
            unsigned short* wrow = Wx2 + (size_t)n * 128 + 8 * gl;
            uint4 o;
            o.x = (unsigned)f2bf(wa0.x) | ((unsigned)f2bf(wa0.y) << 16);
            o.y = (unsigned)f2bf(wa0.z) | ((unsigned)f2bf(wa0.w) << 16);
            o.z = (unsigned)f2bf(wa1.x) | ((unsigned)f2bf(wa1.y) << 16);
            o.w = (unsigned)f2bf(wa1.z) | ((unsigned)f2bf(wa1.w) << 16);
            *(uint4*)wrow = o;
            if (gl == 0) {
                float4 o1; o1.x = aacc[0]; o1.y = aacc[1]; o1.z = aacc[2]; o1.w = aacc[3];
                float4 o2; o2.x = aacc[4]; o2.y = aacc[5]; o2.z = aacc[6]; o2.w = aacc[7];
                ((float4*)asrc2)[n] = o1;
                ((float4*)adst2)[n] = o2;
            }
        }
    }
}

// ---------------------------------------------------------------------------
// Fused GAT layer-2 aggregate + FC head, register-slimmed the same way.
// ---------------------------------------------------------------------------
__global__ __launch_bounds__(512, 8) void k_msg0(
    const int* __restrict__ rowptr, const int* __restrict__ esrc,
    const float* __restrict__ asrc, const float* __restrict__ adst,
    const unsigned short* __restrict__ Wx,
    const float* __restrict__ fc1w, const float* __restrict__ fc1b,
    const float* __restrict__ fc2w, const float* __restrict__ fc2b,
    float* __restrict__ out, int N)
{
    __shared__ float fc1s[8192];            // 32KB: fc1w [c][j]
    int tid = threadIdx.x;
    for (int i = tid; i < 8192; i += 512) fc1s[i] = fc1w[i];
    __syncthreads();

    int lane = tid & 63;
    int grp = lane >> 4;
    int gl = lane & 15;
    int wbase = lane & 48;
    int gw = (blockIdx.x * blockDim.x + tid) >> 6;
    int waves = (gridDim.x * blockDim.x) >> 6;

    float b2 = fc2b[0];

    for (int m = gw; m * 4 < N; m += waves) {
        int n = m * 4 + grp;
        bool nv = n < N;
        int beg = nv ? rowptr[n] : 0;
        int end = nv ? rowptr[n + 1] : 0;
        float4 ad = {0,0,0,0};
        if (nv) ad = ((const float4*)adst)[n];

        float d0 = 0.f, d1 = 0.f, d2 = 0.f, d3 = 0.f;
        for (int c = beg; c < end; c += 16) {
            int e = c + gl;
            bool v = e < end;
            int s = v ? esrc[e] : 0;
            float4 a = ((const float4*)asrc)[s];
            if (v) {
                d0 += fexp(lrelu02(a.x + ad.x));
                d1 += fexp(lrelu02(a.y + ad.y));
                d2 += fexp(lrelu02(a.z + ad.z));
                d3 += fexp(lrelu02(a.w + ad.w));
            }
        }
#pragma unroll
        for (int off = 8; off; off >>= 1) {
            d0 += __shfl_xor(d0, off, 64);
            d1 += __shfl_xor(d1, off, 64);
            d2 += __shfl_xor(d2, off, 64);
            d3 += __shfl_xor(d3, off, 64);
        }
        float r0 = __builtin_amdgcn_rcpf(d0 + 2e-9f);
        float r1 = __builtin_amdgcn_rcpf(d1 + 2e-9f);
        float r2 = __builtin_amdgcn_rcpf(d2 + 2e-9f);
        float r3 = __builtin_amdgcn_rcpf(d3 + 2e-9f);

        float4 acc0 = {0,0,0,0}, acc1 = {0,0,0,0};
        for (int c = beg; c < end; c += 16) {
            int e = c + gl;
            bool v = e < end;
            int s = v ? esrc[e] : 0;
            float4 a = ((const float4*)asrc)[s];
            float cf = 0.f;
            if (v) {
                cf = fexp(lrelu02(a.x + ad.x)) * r0
                   + fexp(lrelu02(a.y + ad.y)) * r1
                   + fexp(lrelu02(a.z + ad.z)) * r2
                   + fexp(lrelu02(a.w + ad.w)) * r3;
            }
#pragma unroll 4
            for (int jj = 0; jj < 16; ++jj) {
                float cj = __shfl(cf, wbase + jj, 64);
                if (cj > 0.f) {
                    int sj = __shfl(s, wbase + jj, 64);
                    uint4 w = ((const uint4*)(Wx + (size_t)sj * 128))[gl];
                    float4 lo, hi; unpack8(w, lo, hi);
                    acc0.x = fmaf(cj, lo.x, acc0.x); acc0.y = fmaf(cj, lo.y, acc0.y);
                    acc0.z = fmaf(cj, lo.z, acc0.z); acc0.w = fmaf(cj, lo.w, acc0.w);
                    acc1.x = fmaf(cj, hi.x, acc1.x); acc1.y = fmaf(cj, hi.y, acc1.y);
                    acc1.z = fmaf(cj, hi.z, acc1.z); acc1.w = fmaf(cj, hi.w, acc1.w);
                }
            }
        }
        // x = elu(acc/4); h = relu(x@fc1+b1); out = h@fc2 + b2
        acc0.x *= 0.25f; acc0.y *= 0.25f; acc0.z *= 0.25f; acc0.w *= 0.25f;
        acc1.x *= 0.25f; acc1.y *= 0.25f; acc1.z *= 0.25f; acc1.w *= 0.25f;
        acc0.x = acc0.x > 0.f ? acc0.x : expm1f(acc0.x);
        acc0.y = acc0.y > 0.f ? acc0.y : expm1f(acc0.y);
        acc0.z = acc0.z > 0.f ? acc0.z : expm1f(acc0.z);
        acc0.w = acc0.w > 0.f ? acc0.w : expm1f(acc0.w);
        acc1.x = acc1.x > 0.f ? acc1.x : expm1f(acc1.x);
        acc1.y = acc1.y > 0.f ? acc1.y : expm1f(acc1.y);
        acc1.z = acc1.z > 0.f ? acc1.z : expm1f(acc1.z);
        acc1.w = acc1.w > 0.f ? acc1.w : expm1f(acc1.w);
        float xo[8] = {acc0.x,acc0.y,acc0.z,acc0.w, acc1.x,acc1.y,acc1.z,acc1.w};

        float4 hacc = *(const float4*)&fc1b[4 * gl];
        for (int j = 0; j < 16; ++j) {
            int src = wbase + j;
#pragma unroll
            for (int e = 0; e < 8; ++e) {
                float xv = __shfl(xo[e], src, 64);
                float4 w = *(const float4*)&fc1s[(8*j + e) * 64 + 4 * gl];
                hacc.x = fmaf(xv, w.x, hacc.x); hacc.y = fmaf(xv, w.y, hacc.y);
                hacc.z = fmaf(xv, w.z, hacc.z); hacc.w = fmaf(xv, w.w, hacc.w);
            }
        }
        float4 w2v = *(const float4*)&fc2w[4 * gl];
        float r = fmaxf(hacc.x, 0.f) * w2v.x + fmaxf(hacc.y, 0.f) * w2v.y
                + fmaxf(hacc.z, 0.f) * w2v.z + fmaxf(hacc.w, 0.f) * w2v.w;
#pragma unroll
        for (int off = 8; off; off >>= 1) r += __shfl_xor(r, off, 64);
        if (nv && gl == 0) out[n] = r + b2;
    }
}

extern "C" void kernel_launch(void* const* d_in, const int* in_sizes, int n_in,
                              void* d_out, int out_size, void* d_ws, size_t ws_size,
                              hipStream_t stream)
{
    const float* nf   = (const float*)d_in[0];
    const int*   ei   = (const int*)  d_in[1];
    const float* ts   = (const float*)d_in[2];
    const float* Wih0 = (const float*)d_in[3];
    const float* Whh0 = (const float*)d_in[4];
    const float* b0   = (const float*)d_in[5];
    const float* Wih1 = (const float*)d_in[6];
    const float* Whh1 = (const float*)d_in[7];
    const float* b1   = (const float*)d_in[8];
    const float* W1   = (const float*)d_in[9];
    const float* A1   = (const float*)d_in[10];
    const float* W2   = (const float*)d_in[11];
    const float* A2   = (const float*)d_in[12];
    const float* fc1w = (const float*)d_in[13];
    const float* fc1b = (const float*)d_in[14];
    const float* fc2w = (const float*)d_in[15];
    const float* fc2b = (const float*)d_in[16];

    int N = in_sizes[0] / 16;
    int E = in_sizes[1] / 2;
    int T = in_sizes[2] / 3;

    char* ws = (char*)d_ws;
    size_t off = 0;
    auto alloc = [&](size_t bytes) {
        char* p = ws + off;
        off = (off + bytes + 255) & ~(size_t)255;
        return p;
    };
    float* tsb    = (float*)alloc(512);
    float* attfix = (float*)alloc(64);
    int*   flags  = (int*)  alloc(64);
    float* m2g    = (float*)alloc(1024 * sizeof(float));
    float* asrc   = (float*)alloc((size_t)N * 4 * sizeof(float));
    float* adst   = (float*)alloc((size_t)N * 4 * sizeof(float));
    float* asrc2  = (float*)alloc((size_t)N * 4 * sizeof(float));
    float* adst2  = (float*)alloc((size_t)N * 4 * sizeof(float));
    int*   rowptr = (int*)  alloc((size_t)(N + 1) * sizeof(int));
    int*   esrc   = (int*)  alloc((size_t)E * sizeof(int));
    int*   epos   = (int*)  alloc((size_t)E * sizeof(int));
    int*   deg    = (int*)  alloc((size_t)N * sizeof(int));
    int*   bsum   = (int*)  alloc(512 * sizeof(int));
    unsigned short* bufA = (unsigned short*)alloc((size_t)N * 128 * sizeof(unsigned short));
    unsigned short* bufC = (unsigned short*)alloc((size_t)N * 128 * sizeof(unsigned short));

    int NCH = (N + 2047) / 2048;

    hipMemsetAsync(deg, 0, (size_t)N * sizeof(int), stream);
    hipMemsetAsync(flags, 0, 64, stream);

    // ---- mega-front: LSTM(f16 dot2) || (hist -> scan -> scatter) || att1P || Wxp(bf16) || M2 ----
    k_front<<<256, 512, 0, stream>>>(
        ts, Wih0, Whh0, b0, Wih1, Whh1, b1, W1, A1, W2, A2,
        tsb, attfix, m2g,
        ei, deg, epos, nf, bufA, asrc, adst,
        rowptr, bsum, esrc, flags,
        N, E, T, NCH);

    // ---- layer-1 aggregate + layer-2 projections (fused) ----
    k_msg1<<<1024, 512, 0, stream>>>(rowptr, esrc, asrc, adst, bufA, tsb, attfix,
                                     W2, m2g, bufC, asrc2, adst2, N);

    // ---- layer-2 aggregate + FC head (fused) ----
    k_msg0<<<1024, 512, 0, stream>>>(rowptr, esrc, asrc2, adst2, bufC,
                                     fc1w, fc1b, fc2w, fc2b, (float*)d_out, N);
}

// Round 16
// 478.634 us; speedup vs baseline: 2.5778x; 2.5778x over previous
//
#include <hip/hip_runtime.h>
#include <math.h>

#define DEV __device__ __forceinline__

#define LOG2E 1.4426950408889634f

typedef _Float16 h2v __attribute__((ext_vector_type(2)));

DEV float fexp(float x)  { return __builtin_amdgcn_exp2f(LOG2E * x); }
DEV float fsigm(float x) { return __builtin_amdgcn_rcpf(1.0f + __builtin_amdgcn_exp2f(-LOG2E * x)); }
DEV float ftanh(float x) { return 1.0f - 2.0f * __builtin_amdgcn_rcpf(__builtin_amdgcn_exp2f(2.0f * LOG2E * x) + 1.0f); }
DEV float lrelu02(float x) { return x > 0.0f ? x : 0.2f * x; }
DEV float fdot2(h2v a, h2v b, float c) { return __builtin_amdgcn_fdot2(a, b, c, false); }
DEV int aload(const int* p) {
    return __hip_atomic_load(p, __ATOMIC_RELAXED, __HIP_MEMORY_SCOPE_AGENT);
}
DEV void astore(int* p, int v) {
    __hip_atomic_store(p, v, __ATOMIC_RELAXED, __HIP_MEMORY_SCOPE_AGENT);
}
DEV unsigned short f2bf(float f) {
    unsigned u = __float_as_uint(f);
    return (unsigned short)((u + 0x7FFFu + ((u >> 16) & 1u)) >> 16);
}
DEV void unpack8(uint4 w, float4& lo, float4& hi) {
    lo.x = __uint_as_float(w.x << 16); lo.y = __uint_as_float(w.x & 0xFFFF0000u);
    lo.z = __uint_as_float(w.y << 16); lo.w = __uint_as_float(w.y & 0xFFFF0000u);
    hi.x = __uint_as_float(w.z << 16); hi.y = __uint_as_float(w.z & 0xFFFF0000u);
    hi.z = __uint_as_float(w.w << 16); hi.w = __uint_as_float(w.w & 0xFFFF0000u);
}
#define QB(v, ctrl) __int_as_float(__builtin_amdgcn_mov_dpp(__float_as_int(v), ctrl, 0xF, 0xF, true))

// ---------------------------------------------------------------------------
// Mega-front (r13's best version): LSTM f16-dot2 || hist->scan->scatter ||
// att1P || Wxp(bf16) || M2.
// ---------------------------------------------------------------------------
__global__ __launch_bounds__(512, 2) void k_front(
    const float* __restrict__ ts,
    const float* __restrict__ Wih0, const float* __restrict__ Whh0, const float* __restrict__ b0,
    const float* __restrict__ Wih1, const float* __restrict__ Whh1, const float* __restrict__ b1,
    const float* __restrict__ W1, const float* __restrict__ A1,
    const float* __restrict__ W2, const float* __restrict__ A2,
    float* __restrict__ tsb, float* __restrict__ attfix, float* __restrict__ m2g,
    const int* __restrict__ ei, int* __restrict__ deg, int* __restrict__ epos,
    const float* __restrict__ nf, unsigned short* __restrict__ Wxp,
    float* __restrict__ asrcP, float* __restrict__ adstP,
    int* __restrict__ rowptr, int* __restrict__ bsum,
    int* __restrict__ esrc, int* __restrict__ flags,
    int N, int E, int T, int NCH)
{
    __shared__ __align__(16) _Float16 h0h[2][64], h1h[2][64];
    __shared__ __align__(16) float tsbig[21504];   // 84KB pad -> 1 block/CU
    __shared__ float m1s[128];
    __shared__ int iwsum[8];
    __shared__ int stmp[512];
    const int tid = threadIdx.x;
    const int bid = blockIdx.x;

    auto signalflag = [&](int* f) {
        __syncthreads();
        if (tid == 0) {
            __threadfence();
            __hip_atomic_fetch_add(f, 1, __ATOMIC_RELEASE, __HIP_MEMORY_SCOPE_AGENT);
        }
    };
    auto waitflag = [&](int* f, int tgt) {
        if (tid == 0) {
            while (__hip_atomic_load(f, __ATOMIC_ACQUIRE, __HIP_MEMORY_SCOPE_AGENT) < tgt)
                __builtin_amdgcn_s_sleep(8);
        }
        __syncthreads();
    };

    if (bid == 0) {
        // ================= LSTM =================
        const int seg = tid >> 8;
        const int idx = tid & 255;
        const int u = idx >> 2;
        const int q = idx & 3;
        const int row = q * 64 + u;
        float* tss = tsbig;

        for (int i = tid; i < 3 * T && i < 512; i += 512) tss[i] = ts[i];
        if (tid < 64) {
            h0h[0][tid] = (_Float16)0.f; h0h[1][tid] = (_Float16)0.f;
            h1h[0][tid] = (_Float16)0.f; h1h[1][tid] = (_Float16)0.f;
        }
        __syncthreads();

        if (seg == 0) {
            h2v wa[32];
            float wih[3];
            float bias = b0[row];
            wih[0] = Wih0[row*3+0]; wih[1] = Wih0[row*3+1]; wih[2] = Wih0[row*3+2];
#pragma unroll
            for (int k = 0; k < 32; k++) {
                h2v w; w.x = (_Float16)Whh0[row*64 + 2*k]; w.y = (_Float16)Whh0[row*64 + 2*k + 1];
                wa[k] = w;
            }
            float creg = 0.0f;
            for (int k = 0; k <= T; ++k) {
                if (k < T) {
                    const h2v* hp = (const h2v*)h0h[(k + 1) & 1];
                    float a0 = bias, a1 = 0.f, a2 = 0.f, a3 = 0.f;
                    a0 = fmaf(tss[3*k+0], wih[0], a0);
                    a1 = fmaf(tss[3*k+1], wih[1], a1);
                    a2 = fmaf(tss[3*k+2], wih[2], a2);
#pragma unroll
                    for (int p = 0; p < 32; p += 4) {
                        a0 = fdot2(wa[p+0], hp[p+0], a0);
                        a1 = fdot2(wa[p+1], hp[p+1], a1);
                        a2 = fdot2(wa[p+2], hp[p+2], a2);
                        a3 = fdot2(wa[p+3], hp[p+3], a3);
                    }
                    float mine = (a0 + a1) + (a2 + a3);
                    float gi = QB(mine, 0x00);
                    float gf = QB(mine, 0x55);
                    float gg = QB(mine, 0xAA);
                    float go = QB(mine, 0xFF);
                    creg = fsigm(gf) * creg + fsigm(gi) * ftanh(gg);
                    float h = fsigm(go) * ftanh(creg);
                    if (q == 0) h0h[k & 1][u] = (_Float16)h;
                }
                __syncthreads();
            }
            if (tid < 128) {
                const _Float16* hf = h1h[(T - 1) & 1];
                float acc = 0.f;
#pragma unroll
                for (int kk = 0; kk < 64; kk++)
                    acc = fmaf((float)hf[kk], W1[(16 + kk) * 128 + tid], acc);
                tsb[tid] = acc;
                m1s[tid] = acc;
            }
            __syncthreads();
            if (tid < 8) {
                int half = tid >> 2, h = tid & 3;
                const float* a1p = A1 + (size_t)half * 512 + h;
                float acc = 0.f;
                for (int c = 0; c < 128; c++) acc = fmaf(m1s[c], a1p[c * 4], acc);
                attfix[tid] = acc;
            }
        } else {
            h2v wa[32], wb[32];
            float bias = b1[row];
#pragma unroll
            for (int k = 0; k < 32; k++) {
                h2v w; w.x = (_Float16)Whh1[row*64 + 2*k]; w.y = (_Float16)Whh1[row*64 + 2*k + 1];
                wa[k] = w;
            }
#pragma unroll
            for (int k = 0; k < 32; k++) {
                h2v w; w.x = (_Float16)Wih1[row*64 + 2*k]; w.y = (_Float16)Wih1[row*64 + 2*k + 1];
                wb[k] = w;
            }
            float creg = 0.0f;
            for (int k = 0; k <= T; ++k) {
                if (k >= 1) {
                    const h2v* h1p = (const h2v*)h1h[k & 1];
                    const h2v* h0p = (const h2v*)h0h[(k + 1) & 1];
                    float a0 = bias, a1 = 0.f, a2 = 0.f, a3 = 0.f;
#pragma unroll
                    for (int p = 0; p < 32; p += 4) {
                        a0 = fdot2(wa[p+0], h1p[p+0], a0);
                        a1 = fdot2(wa[p+1], h1p[p+1], a1);
                        a2 = fdot2(wa[p+2], h1p[p+2], a2);
                        a3 = fdot2(wa[p+3], h1p[p+3], a3);
                    }
#pragma unroll
                    for (int p = 0; p < 32; p += 4) {
                        a0 = fdot2(wb[p+0], h0p[p+0], a0);
                        a1 = fdot2(wb[p+1], h0p[p+1], a1);
                        a2 = fdot2(wb[p+2], h0p[p+2], a2);
                        a3 = fdot2(wb[p+3], h0p[p+3], a3);
                    }
                    float mine = (a0 + a1) + (a2 + a3);
                    float gi = QB(mine, 0x00);
                    float gf = QB(mine, 0x55);
                    float gg = QB(mine, 0xAA);
                    float go = QB(mine, 0xFF);
                    creg = fsigm(gf) * creg + fsigm(gi) * ftanh(gg);
                    float h = fsigm(go) * ftanh(creg);
                    if (q == 0) h1h[(k + 1) & 1][u] = (_Float16)h;
                }
                __syncthreads();
            }
            __syncthreads();
        }
        return;
    }

    // ================= workers =================
    const int W = gridDim.x - 1;
    const int wid = bid - 1;

    {
        int g = wid * 512 + tid, stride = W * 512;
        for (int e = g; e < E; e += stride)
            epos[e] = atomicAdd(&deg[ei[E + e]], 1);
    }
    signalflag(&flags[0]);

    if (wid < NCH) {
        waitflag(&flags[0], W);
        int base = wid * 2048 + tid * 4;
        int d0 = base + 0 < N ? aload(&deg[base + 0]) : 0;
        int d1 = base + 1 < N ? aload(&deg[base + 1]) : 0;
        int d2 = base + 2 < N ? aload(&deg[base + 2]) : 0;
        int d3 = base + 3 < N ? aload(&deg[base + 3]) : 0;
        int tsum = d0 + d1 + d2 + d3;
        int lane = tid & 63, wv = tid >> 6;
        int incl = tsum;
#pragma unroll
        for (int off = 1; off < 64; off <<= 1) {
            int t = __shfl_up(incl, off, 64);
            if (lane >= off) incl += t;
        }
        if (lane == 63) iwsum[wv] = incl;
        __syncthreads();
        int woff = 0;
#pragma unroll
        for (int w = 0; w < 8; w++) if (w < wv) woff += iwsum[w];
        int tex = woff + incl - tsum;
        if (base + 0 < N) rowptr[base + 0] = tex;
        if (base + 1 < N) rowptr[base + 1] = tex + d0;
        if (base + 2 < N) rowptr[base + 2] = tex + d0 + d1;
        if (base + 3 < N) rowptr[base + 3] = tex + d0 + d1 + d2;
        if (tid == 511) astore(&bsum[wid], woff + incl);
        signalflag(&flags[1]);
        waitflag(&flags[2], 1);
        int off2 = aload(&bsum[wid]);
#pragma unroll
        for (int i = 0; i < 4; i++) {
            int idx = base + i;
            if (idx < N) {
                int v = rowptr[idx] + off2;
                astore(&rowptr[idx], v);
            }
        }
        if (wid == 0 && tid == 0) astore(&rowptr[N], E);
        signalflag(&flags[3]);
    } else if (wid == NCH) {
        waitflag(&flags[1], NCH);
        int v = tid < NCH ? aload(&bsum[tid]) : 0;
        stmp[tid] = v;
        __syncthreads();
        for (int off = 1; off < 512; off <<= 1) {
            int t = (tid >= off) ? stmp[tid - off] : 0;
            __syncthreads();
            stmp[tid] += t;
            __syncthreads();
        }
        if (tid < NCH) astore(&bsum[tid], stmp[tid] - v);
        signalflag(&flags[2]);
#pragma unroll
        for (int e = tid; e < 1024; e += 512) {
            int k = e >> 3, h8 = e & 7, half = h8 >> 2, h = h8 & 3;
            const float* w2p = W2 + (size_t)k * 128;
            const float* a2p = A2 + (size_t)half * 512 + h;
            float acc = 0.f;
            for (int c = 0; c < 128; c++) acc = fmaf(w2p[c], a2p[c * 4], acc);
            m2g[e] = acc;
        }
    } else {
        const int AW = W - NCH - 1;
        const int aw = wid - NCH - 1;
        if (tid < 128) {
            int k = tid >> 3, h8 = tid & 7, half = h8 >> 2, h = h8 & 3;
            const float* a1p = A1 + (size_t)half * 512 + h;
            const float* w1p = W1 + (size_t)k * 128;
            float acc = 0.f;
            for (int c = 0; c < 128; c++) acc = fmaf(w1p[c], a1p[c * 4], acc);
            m1s[tid] = acc;
        }
        __syncthreads();
        float m1r[128];
#pragma unroll
        for (int i = 0; i < 128; i++) m1r[i] = m1s[i];
        {
            int gt = aw * 512 + tid;
            int tstride = AW * 512;
            for (int n = gt; n < N; n += tstride) {
                const float4* nfr = (const float4*)(nf + (size_t)n * 16);
                float4 f0 = nfr[0], f1 = nfr[1], f2 = nfr[2], f3 = nfr[3];
                float xk[16] = {f0.x,f0.y,f0.z,f0.w, f1.x,f1.y,f1.z,f1.w,
                                f2.x,f2.y,f2.z,f2.w, f3.x,f3.y,f3.z,f3.w};
                float as0=0,as1=0,as2=0,as3=0, ad0=0,ad1=0,ad2=0,ad3=0;
#pragma unroll
                for (int k = 0; k < 16; k++) {
                    float xv = xk[k];
                    as0 = fmaf(xv, m1r[k*8+0], as0); as1 = fmaf(xv, m1r[k*8+1], as1);
                    as2 = fmaf(xv, m1r[k*8+2], as2); as3 = fmaf(xv, m1r[k*8+3], as3);
                    ad0 = fmaf(xv, m1r[k*8+4], ad0); ad1 = fmaf(xv, m1r[k*8+5], ad1);
                    ad2 = fmaf(xv, m1r[k*8+6], ad2); ad3 = fmaf(xv, m1r[k*8+7], ad3);
                }
                float4 o1; o1.x=as0; o1.y=as1; o1.z=as2; o1.w=as3;
                float4 o2; o2.x=ad0; o2.y=ad1; o2.z=ad2; o2.w=ad3;
                ((float4*)asrcP)[n] = o1;
                ((float4*)adstP)[n] = o2;
            }
        }
        {
            int lane = tid & 63;
            int bw = aw * 8 + (tid >> 6);
            int half = bw & 1;
            int col = lane + 64 * half;
            float wreg[16];
#pragma unroll
            for (int k = 0; k < 16; k++) wreg[k] = W1[k * 128 + col];
            int nstride = AW * 4;
            for (int n = (bw >> 1); n < N; n += nstride) {
                int nu = __builtin_amdgcn_readfirstlane(n);
                const float4* xr = (const float4*)(nf + (size_t)nu * 16);
                float4 x0 = xr[0], x1 = xr[1], x2 = xr[2], x3 = xr[3];
                float acc = 0.f;
                acc = fmaf(x0.x, wreg[0],  acc); acc = fmaf(x0.y, wreg[1],  acc);
                acc = fmaf(x0.z, wreg[2],  acc); acc = fmaf(x0.w, wreg[3],  acc);
                acc = fmaf(x1.x, wreg[4],  acc); acc = fmaf(x1.y, wreg[5],  acc);
                acc = fmaf(x1.z, wreg[6],  acc); acc = fmaf(x1.w, wreg[7],  acc);
                acc = fmaf(x2.x, wreg[8],  acc); acc = fmaf(x2.y, wreg[9],  acc);
                acc = fmaf(x2.z, wreg[10], acc); acc = fmaf(x2.w, wreg[11], acc);
                acc = fmaf(x3.x, wreg[12], acc); acc = fmaf(x3.y, wreg[13], acc);
                acc = fmaf(x3.z, wreg[14], acc); acc = fmaf(x3.w, wreg[15], acc);
                Wxp[(size_t)nu * 128 + col] = f2bf(acc);
            }
        }
    }

    waitflag(&flags[3], NCH);
    {
        int g = wid * 512 + tid, stride = W * 512;
        for (int e = g; e < E; e += stride) {
            int s = ei[e], d = ei[E + e];
            esrc[aload(&rowptr[d]) + epos[e]] = s;
        }
    }
}

// ---------------------------------------------------------------------------
// Fused GAT layer-1 aggregate + layer-2 projections (r12's best measured
// variant: exp-cached chunk-0, shfl broadcast, (512,8) -> spill@72% occ,
// empirically fastest at 203us).
// ---------------------------------------------------------------------------
__global__ __launch_bounds__(512, 8) void k_msg1(
    const int* __restrict__ rowptr, const int* __restrict__ esrc,
    const float* __restrict__ asrc, const float* __restrict__ adst,
    const unsigned short* __restrict__ Wx, const float* __restrict__ tsb,
    const float* __restrict__ attfix,
    const float* __restrict__ W2, const float* __restrict__ m2g,
    unsigned short* __restrict__ Wx2, float* __restrict__ asrc2,
    float* __restrict__ adst2, int N)
{
    __shared__ unsigned short w2s[16384];   // 32KB: W2 bf16 [k][c]
    __shared__ float m2p[128 * 9];          // padded M2
    int tid = threadIdx.x;
    for (int i = tid; i < 16384; i += 512) w2s[i] = f2bf(W2[i]);
    for (int i = tid; i < 1024; i += 512) m2p[(i >> 3) * 9 + (i & 7)] = m2g[i];
    __syncthreads();

    int lane = tid & 63;
    int grp = lane >> 4;
    int gl = lane & 15;
    int wbase = lane & 48;
    int gw = (blockIdx.x * blockDim.x + tid) >> 6;
    int waves = (gridDim.x * blockDim.x) >> 6;

    float4 tb0 = ((const float4*)tsb)[gl*2];
    float4 tb1 = ((const float4*)tsb)[gl*2+1];
    float cc0 = attfix[0] + attfix[4];
    float cc1 = attfix[1] + attfix[5];
    float cc2 = attfix[2] + attfix[6];
    float cc3 = attfix[3] + attfix[7];

    for (int m = gw; m * 4 < N; m += waves) {
        int n = m * 4 + grp;
        bool nv = n < N;
        int beg = nv ? rowptr[n] : 0;
        int end = nv ? rowptr[n + 1] : 0;
        float4 ad = {0,0,0,0};
        if (nv) ad = ((const float4*)adst)[n];
        ad.x += cc0; ad.y += cc1; ad.z += cc2; ad.w += cc3;

        int e0 = beg + gl;
        bool v0 = e0 < end;
        int s0 = v0 ? esrc[e0] : 0;
        float4 a0 = ((const float4*)asrc)[s0];
        float x0 = v0 ? fexp(lrelu02(a0.x + ad.x)) : 0.f;
        float x1 = v0 ? fexp(lrelu02(a0.y + ad.y)) : 0.f;
        float x2 = v0 ? fexp(lrelu02(a0.z + ad.z)) : 0.f;
        float x3 = v0 ? fexp(lrelu02(a0.w + ad.w)) : 0.f;
        float d0 = x0, d1 = x1, d2 = x2, d3 = x3;
        for (int c = beg + 16; c < end; c += 16) {
            int e = c + gl;
            bool v = e < end;
            int s = v ? esrc[e] : 0;
            float4 a = ((const float4*)asrc)[s];
            if (v) {
                d0 += fexp(lrelu02(a.x + ad.x));
                d1 += fexp(lrelu02(a.y + ad.y));
                d2 += fexp(lrelu02(a.z + ad.z));
                d3 += fexp(lrelu02(a.w + ad.w));
            }
        }
#pragma unroll
        for (int off = 8; off; off >>= 1) {
            d0 += __shfl_xor(d0, off, 64);
            d1 += __shfl_xor(d1, off, 64);
            d2 += __shfl_xor(d2, off, 64);
            d3 += __shfl_xor(d3, off, 64);
        }
        float r0 = __builtin_amdgcn_rcpf(d0 + 2e-9f);
        float r1 = __builtin_amdgcn_rcpf(d1 + 2e-9f);
        float r2 = __builtin_amdgcn_rcpf(d2 + 2e-9f);
        float r3 = __builtin_amdgcn_rcpf(d3 + 2e-9f);

        float csum = d0*r0 + d1*r1 + d2*r2 + d3*r3;
        float4 acc0, acc1;
        acc0.x = csum*tb0.x; acc0.y = csum*tb0.y; acc0.z = csum*tb0.z; acc0.w = csum*tb0.w;
        acc1.x = csum*tb1.x; acc1.y = csum*tb1.y; acc1.z = csum*tb1.z; acc1.w = csum*tb1.w;

        float coef = x0*r0 + x1*r1 + x2*r2 + x3*r3;
#pragma unroll 4
        for (int jj = 0; jj < 16; ++jj) {
            float cj = __shfl(coef, wbase + jj, 64);
            if (cj > 0.f) {
                int sj = __shfl(s0, wbase + jj, 64);
                uint4 w = ((const uint4*)(Wx + (size_t)sj * 128))[gl];
                float4 lo, hi; unpack8(w, lo, hi);
                acc0.x = fmaf(cj, lo.x, acc0.x); acc0.y = fmaf(cj, lo.y, acc0.y);
                acc0.z = fmaf(cj, lo.z, acc0.z); acc0.w = fmaf(cj, lo.w, acc0.w);
                acc1.x = fmaf(cj, hi.x, acc1.x); acc1.y = fmaf(cj, hi.y, acc1.y);
                acc1.z = fmaf(cj, hi.z, acc1.z); acc1.w = fmaf(cj, hi.w, acc1.w);
            }
        }
        for (int c = beg + 16; c < end; c += 16) {
            int e = c + gl;
            bool v = e < end;
            int s = v ? esrc[e] : 0;
            float4 a = ((const float4*)asrc)[s];
            float cf = 0.f;
            if (v) {
                cf = fexp(lrelu02(a.x + ad.x)) * r0
                   + fexp(lrelu02(a.y + ad.y)) * r1
                   + fexp(lrelu02(a.z + ad.z)) * r2
                   + fexp(lrelu02(a.w + ad.w)) * r3;
            }
#pragma unroll 4
            for (int jj = 0; jj < 16; ++jj) {
                float cj = __shfl(cf, wbase + jj, 64);
                if (cj > 0.f) {
                    int sj = __shfl(s, wbase + jj, 64);
                    uint4 w = ((const uint4*)(Wx + (size_t)sj * 128))[gl];
                    float4 lo, hi; unpack8(w, lo, hi);
                    acc0.x = fmaf(cj, lo.x, acc0.x); acc0.y = fmaf(cj, lo.y, acc0.y);
                    acc0.z = fmaf(cj, lo.z, acc0.z); acc0.w = fmaf(cj, lo.w, acc0.w);
                    acc1.x = fmaf(cj, hi.x, acc1.x); acc1.y = fmaf(cj, hi.y, acc1.y);
                    acc1.z = fmaf(cj, hi.z, acc1.z); acc1.w = fmaf(cj, hi.w, acc1.w);
                }
            }
        }
        // x1 = elu(acc/4)
        acc0.x *= 0.25f; acc0.y *= 0.25f; acc0.z *= 0.25f; acc0.w *= 0.25f;
        acc1.x *= 0.25f; acc1.y *= 0.25f; acc1.z *= 0.25f; acc1.w *= 0.25f;
        acc0.x = acc0.x > 0.f ? acc0.x : expm1f(acc0.x);
        acc0.y = acc0.y > 0.f ? acc0.y : expm1f(acc0.y);
        acc0.z = acc0.z > 0.f ? acc0.z : expm1f(acc0.z);
        acc0.w = acc0.w > 0.f ? acc0.w : expm1f(acc0.w);
        acc1.x = acc1.x > 0.f ? acc1.x : expm1f(acc1.x);
        acc1.y = acc1.y > 0.f ? acc1.y : expm1f(acc1.y);
        acc1.z = acc1.z > 0.f ? acc1.z : expm1f(acc1.z);
        acc1.w = acc1.w > 0.f ? acc1.w : expm1f(acc1.w);

        float xo[8] = {acc0.x,acc0.y,acc0.z,acc0.w, acc1.x,acc1.y,acc1.z,acc1.w};

        // Wx2[n][8gl..8gl+8) = sum_k x1[k] * W2[k][c], x1 broadcast via shfl
        float4 wa0 = {0,0,0,0}, wa1 = {0,0,0,0};
        const uint4* w2v4 = (const uint4*)w2s;
#pragma unroll 2
        for (int j = 0; j < 16; ++j) {
            int src = wbase + j;
            float xk0 = __shfl(xo[0], src, 64);
            float xk1 = __shfl(xo[1], src, 64);
            float xk2 = __shfl(xo[2], src, 64);
            float xk3 = __shfl(xo[3], src, 64);
            float xk4 = __shfl(xo[4], src, 64);
            float xk5 = __shfl(xo[5], src, 64);
            float xk6 = __shfl(xo[6], src, 64);
            float xk7 = __shfl(xo[7], src, 64);
            float xks[8] = {xk0,xk1,xk2,xk3,xk4,xk5,xk6,xk7};
#pragma unroll
            for (int e = 0; e < 8; ++e) {
                uint4 w = w2v4[(8*j + e) * 16 + gl];
                float4 lo, hi; unpack8(w, lo, hi);
                float xv = xks[e];
                wa0.x = fmaf(xv, lo.x, wa0.x); wa0.y = fmaf(xv, lo.y, wa0.y);
                wa0.z = fmaf(xv, lo.z, wa0.z); wa0.w = fmaf(xv, lo.w, wa0.w);
                wa1.x = fmaf(xv, hi.x, wa1.x); wa1.y = fmaf(xv, hi.y, wa1.y);
                wa1.z = fmaf(xv, hi.z, wa1.z); wa1.w = fmaf(xv, hi.w, wa1.w);
            }
        }
        // att2 partials over own k-range (x values in regs)
        float aacc[8] = {0,0,0,0,0,0,0,0};
#pragma unroll
        for (int kk = 0; kk < 8; ++kk) {
            const float* mrow = &m2p[(8 * gl + kk) * 9];
            float xv = xo[kk];
#pragma unroll
            for (int h = 0; h < 8; ++h) aacc[h] = fmaf(xv, mrow[h], aacc[h]);
        }
#pragma unroll
        for (int off = 8; off; off >>= 1) {
#pragma unroll
            for (int h = 0; h < 8; ++h) aacc[h] += __shfl_xor(aacc[h], off, 64);
        }
        if (nv) {
            unsigned short* wrow = Wx2 + (size_t)n * 128 + 8 * gl;
            uint4 o;
            o.x = (unsigned)f2bf(wa0.x) | ((unsigned)f2bf(wa0.y) << 16);
            o.y = (unsigned)f2bf(wa0.z) | ((unsigned)f2bf(wa0.w) << 16);
            o.z = (unsigned)f2bf(wa1.x) | ((unsigned)f2bf(wa1.y) << 16);
            o.w = (unsigned)f2bf(wa1.z) | ((unsigned)f2bf(wa1.w) << 16);
            *(uint4*)wrow = o;
            if (gl == 0) {
                float4 o1; o1.x = aacc[0]; o1.y = aacc[1]; o1.z = aacc[2]; o1.w = aacc[3];
                float4 o2; o2.x = aacc[4]; o2.y = aacc[5]; o2.z = aacc[6]; o2.w = aacc[7];
                ((float4*)asrc2)[n] = o1;
                ((float4*)adst2)[n] = o2;
            }
        }
    }
}

// ---------------------------------------------------------------------------
// Fused GAT layer-2 aggregate + FC head (r12's variant, (512,8)).
// ---------------------------------------------------------------------------
__global__ __launch_bounds__(512, 8) void k_msg0(
    const int* __restrict__ rowptr, const int* __restrict__ esrc,
    const float* __restrict__ asrc, const float* __restrict__ adst,
    const unsigned short* __restrict__ Wx,
    const float* __restrict__ fc1w, const float* __restrict__ fc1b,
    const float* __restrict__ fc2w, const float* __restrict__ fc2b,
    float* __restrict__ out, int N)
{
    __shared__ float fc1s[8192];            // 32KB: fc1w [c][j]
    int tid = threadIdx.x;
    for (int i = tid; i < 8192; i += 512) fc1s[i] = fc1w[i];
    __syncthreads();

    int lane = tid & 63;
    int grp = lane >> 4;
    int gl = lane & 15;
    int wbase = lane & 48;
    int gw = (blockIdx.x * blockDim.x + tid) >> 6;
    int waves = (gridDim.x * blockDim.x) >> 6;

    float4 b1v = *(const float4*)&fc1b[4 * gl];
    float4 w2v = *(const float4*)&fc2w[4 * gl];
    float b2 = fc2b[0];

    for (int m = gw; m * 4 < N; m += waves) {
        int n = m * 4 + grp;
        bool nv = n < N;
        int beg = nv ? rowptr[n] : 0;
        int end = nv ? rowptr[n + 1] : 0;
        float4 ad = {0,0,0,0};
        if (nv) ad = ((const float4*)adst)[n];

        int e0 = beg + gl;
        bool v0 = e0 < end;
        int s0 = v0 ? esrc[e0] : 0;
        float4 a0 = ((const float4*)asrc)[s0];
        float x0 = v0 ? fexp(lrelu02(a0.x + ad.x)) : 0.f;
        float x1 = v0 ? fexp(lrelu02(a0.y + ad.y)) : 0.f;
        float x2 = v0 ? fexp(lrelu02(a0.z + ad.z)) : 0.f;
        float x3 = v0 ? fexp(lrelu02(a0.w + ad.w)) : 0.f;
        float d0 = x0, d1 = x1, d2 = x2, d3 = x3;
        for (int c = beg + 16; c < end; c += 16) {
            int e = c + gl;
            bool v = e < end;
            int s = v ? esrc[e] : 0;
            float4 a = ((const float4*)asrc)[s];
            if (v) {
                d0 += fexp(lrelu02(a.x + ad.x));
                d1 += fexp(lrelu02(a.y + ad.y));
                d2 += fexp(lrelu02(a.z + ad.z));
                d3 += fexp(lrelu02(a.w + ad.w));
            }
        }
#pragma unroll
        for (int off = 8; off; off >>= 1) {
            d0 += __shfl_xor(d0, off, 64);
            d1 += __shfl_xor(d1, off, 64);
            d2 += __shfl_xor(d2, off, 64);
            d3 += __shfl_xor(d3, off, 64);
        }
        float r0 = __builtin_amdgcn_rcpf(d0 + 2e-9f);
        float r1 = __builtin_amdgcn_rcpf(d1 + 2e-9f);
        float r2 = __builtin_amdgcn_rcpf(d2 + 2e-9f);
        float r3 = __builtin_amdgcn_rcpf(d3 + 2e-9f);

        float4 acc0 = {0,0,0,0}, acc1 = {0,0,0,0};
        float coef = x0*r0 + x1*r1 + x2*r2 + x3*r3;
#pragma unroll 4
        for (int jj = 0; jj < 16; ++jj) {
            float cj = __shfl(coef, wbase + jj, 64);
            if (cj > 0.f) {
                int sj = __shfl(s0, wbase + jj, 64);
                uint4 w = ((const uint4*)(Wx + (size_t)sj * 128))[gl];
                float4 lo, hi; unpack8(w, lo, hi);
                acc0.x = fmaf(cj, lo.x, acc0.x); acc0.y = fmaf(cj, lo.y, acc0.y);
                acc0.z = fmaf(cj, lo.z, acc0.z); acc0.w = fmaf(cj, lo.w, acc0.w);
                acc1.x = fmaf(cj, hi.x, acc1.x); acc1.y = fmaf(cj, hi.y, acc1.y);
                acc1.z = fmaf(cj, hi.z, acc1.z); acc1.w = fmaf(cj, hi.w, acc1.w);
            }
        }
        for (int c = beg + 16; c < end; c += 16) {
            int e = c + gl;
            bool v = e < end;
            int s = v ? esrc[e] : 0;
            float4 a = ((const float4*)asrc)[s];
            float cf = 0.f;
            if (v) {
                cf = fexp(lrelu02(a.x + ad.x)) * r0
                   + fexp(lrelu02(a.y + ad.y)) * r1
                   + fexp(lrelu02(a.z + ad.z)) * r2
                   + fexp(lrelu02(a.w + ad.w)) * r3;
            }
#pragma unroll 4
            for (int jj = 0; jj < 16; ++jj) {
                float cj = __shfl(cf, wbase + jj, 64);
                if (cj > 0.f) {
                    int sj = __shfl(s, wbase + jj, 64);
                    uint4 w = ((const uint4*)(Wx + (size_t)sj * 128))[gl];
                    float4 lo, hi; unpack8(w, lo, hi);
                    acc0.x = fmaf(cj, lo.x, acc0.x); acc0.y = fmaf(cj, lo.y, acc0.y);
                    acc0.z = fmaf(cj, lo.z, acc0.z); acc0.w = fmaf(cj, lo.w, acc0.w);
                    acc1.x = fmaf(cj, hi.x, acc1.x); acc1.y = fmaf(cj, hi.y, acc1.y);
                    acc1.z = fmaf(cj, hi.z, acc1.z); acc1.w = fmaf(cj, hi.w, acc1.w);
                }
            }
        }
        // x = elu(acc/4); h = relu(x@fc1+b1) (x broadcast via shfl); out = h@fc2+b2
        acc0.x *= 0.25f; acc0.y *= 0.25f; acc0.z *= 0.25f; acc0.w *= 0.25f;
        acc1.x *= 0.25f; acc1.y *= 0.25f; acc1.z *= 0.25f; acc1.w *= 0.25f;
        acc0.x = acc0.x > 0.f ? acc0.x : expm1f(acc0.x);
        acc0.y = acc0.y > 0.f ? acc0.y : expm1f(acc0.y);
        acc0.z = acc0.z > 0.f ? acc0.z : expm1f(acc0.z);
        acc0.w = acc0.w > 0.f ? acc0.w : expm1f(acc0.w);
        acc1.x = acc1.x > 0.f ? acc1.x : expm1f(acc1.x);
        acc1.y = acc1.y > 0.f ? acc1.y : expm1f(acc1.y);
        acc1.z = acc1.z > 0.f ? acc1.z : expm1f(acc1.z);
        acc1.w = acc1.w > 0.f ? acc1.w : expm1f(acc1.w);
        float xo[8] = {acc0.x,acc0.y,acc0.z,acc0.w, acc1.x,acc1.y,acc1.z,acc1.w};

        float4 hacc = b1v;
#pragma unroll 2
        for (int j = 0; j < 16; ++j) {
            int src = wbase + j;
            float xk0 = __shfl(xo[0], src, 64);
            float xk1 = __shfl(xo[1], src, 64);
            float xk2 = __shfl(xo[2], src, 64);
            float xk3 = __shfl(xo[3], src, 64);
            float xk4 = __shfl(xo[4], src, 64);
            float xk5 = __shfl(xo[5], src, 64);
            float xk6 = __shfl(xo[6], src, 64);
            float xk7 = __shfl(xo[7], src, 64);
            float xks[8] = {xk0,xk1,xk2,xk3,xk4,xk5,xk6,xk7};
#pragma unroll
            for (int e = 0; e < 8; ++e) {
                float4 w = *(const float4*)&fc1s[(8*j + e) * 64 + 4 * gl];
                hacc.x = fmaf(xks[e], w.x, hacc.x); hacc.y = fmaf(xks[e], w.y, hacc.y);
                hacc.z = fmaf(xks[e], w.z, hacc.z); hacc.w = fmaf(xks[e], w.w, hacc.w);
            }
        }
        float r = fmaxf(hacc.x, 0.f) * w2v.x + fmaxf(hacc.y, 0.f) * w2v.y
                + fmaxf(hacc.z, 0.f) * w2v.z + fmaxf(hacc.w, 0.f) * w2v.w;
#pragma unroll
        for (int off = 8; off; off >>= 1) r += __shfl_xor(r, off, 64);
        if (nv && gl == 0) out[n] = r + b2;
    }
}

extern "C" void kernel_launch(void* const* d_in, const int* in_sizes, int n_in,
                              void* d_out, int out_size, void* d_ws, size_t ws_size,
                              hipStream_t stream)
{
    const float* nf   = (const float*)d_in[0];
    const int*   ei   = (const int*)  d_in[1];
    const float* ts   = (const float*)d_in[2];
    const float* Wih0 = (const float*)d_in[3];
    const float* Whh0 = (const float*)d_in[4];
    const float* b0   = (const float*)d_in[5];
    const float* Wih1 = (const float*)d_in[6];
    const float* Whh1 = (const float*)d_in[7];
    const float* b1   = (const float*)d_in[8];
    const float* W1   = (const float*)d_in[9];
    const float* A1   = (const float*)d_in[10];
    const float* W2   = (const float*)d_in[11];
    const float* A2   = (const float*)d_in[12];
    const float* fc1w = (const float*)d_in[13];
    const float* fc1b = (const float*)d_in[14];
    const float* fc2w = (const float*)d_in[15];
    const float* fc2b = (const float*)d_in[16];

    int N = in_sizes[0] / 16;
    int E = in_sizes[1] / 2;
    int T = in_sizes[2] / 3;

    char* ws = (char*)d_ws;
    size_t off = 0;
    auto alloc = [&](size_t bytes) {
        char* p = ws + off;
        off = (off + bytes + 255) & ~(size_t)255;
        return p;
    };
    float* tsb    = (float*)alloc(512);
    float* attfix = (float*)alloc(64);
    int*   flags  = (int*)  alloc(64);
    float* m2g    = (float*)alloc(1024 * sizeof(float));
    float* asrc   = (float*)alloc((size_t)N * 4 * sizeof(float));
    float* adst   = (float*)alloc((size_t)N * 4 * sizeof(float));
    float* asrc2  = (float*)alloc((size_t)N * 4 * sizeof(float));
    float* adst2  = (float*)alloc((size_t)N * 4 * sizeof(float));
    int*   rowptr = (int*)  alloc((size_t)(N + 1) * sizeof(int));
    int*   esrc   = (int*)  alloc((size_t)E * sizeof(int));
    int*   epos   = (int*)  alloc((size_t)E * sizeof(int));
    int*   deg    = (int*)  alloc((size_t)N * sizeof(int));
    int*   bsum   = (int*)  alloc(512 * sizeof(int));
    unsigned short* bufA = (unsigned short*)alloc((size_t)N * 128 * sizeof(unsigned short));
    unsigned short* bufC = (unsigned short*)alloc((size_t)N * 128 * sizeof(unsigned short));

    int NCH = (N + 2047) / 2048;

    hipMemsetAsync(deg, 0, (size_t)N * sizeof(int), stream);
    hipMemsetAsync(flags, 0, 64, stream);

    // ---- mega-front: LSTM(f16 dot2) || (hist -> scan -> scatter) || att1P || Wxp(bf16) || M2 ----
    k_front<<<256, 512, 0, stream>>>(
        ts, Wih0, Whh0, b0, Wih1, Whh1, b1, W1, A1, W2, A2,
        tsb, attfix, m2g,
        ei, deg, epos, nf, bufA, asrc, adst,
        rowptr, bsum, esrc, flags,
        N, E, T, NCH);

    // ---- layer-1 aggregate + layer-2 projections (fused) ----
    k_msg1<<<1024, 512, 0, stream>>>(rowptr, esrc, asrc, adst, bufA, tsb, attfix,
                                     W2, m2g, bufC, asrc2, adst2, N);

    // ---- layer-2 aggregate + FC head (fused) ----
    k_msg0<<<1024, 512, 0, stream>>>(rowptr, esrc, asrc2, adst2, bufC,
                                     fc1w, fc1b, fc2w, fc2b, (float*)d_out, N);
}